// Round 16
// baseline (338.311 us; speedup 1.0000x reference)
//
#include <hip/hip_runtime.h>
#include <hip/hip_bf16.h>

#define NNODES 100000
#define NEDGES 1600000
#define VOCAB 50000
#define HDIM 256
#define ADIM 64
#define NHEADS 3
#define FDIM 192   // NHEADS*ADIM
#define NGRAPH 64
#define NPART 64

#define CONV_ELEMS (HDIM * FDIM + 128 * 64 + 16 * 128)   // 59392
#define CONV_BLOCKS ((CONV_ELEMS + 255) / 256)            // 232
#define HIST_BLOCKS ((NEDGES + 255) / 256)                // 6250
#define PREP_BLOCKS 3
#define ELVR_BLOCKS ((VOCAB + 3) / 4)                     // 12500
#define PROJ_BLOCKS ((VOCAB + 63) / 64)                   // 782
#define SCAT_BLOCKS ((NEDGES / 8 + 255) / 256)            // 782 (8 edges/thread)
#define NB ((NNODES + 1023) / 1024)                       // 98 scan blocks

typedef __attribute__((ext_vector_type(8))) short bf16x8;  // 8 bf16 = 4 VGPRs
typedef __attribute__((ext_vector_type(4))) float f32x4;

__device__ __forceinline__ float bf2f(unsigned short u) {
  return __uint_as_float((unsigned int)u << 16);
}
__device__ __forceinline__ unsigned short f2bf(float f) {
  unsigned int u = __float_as_uint(f);
  u += 0x7FFFu + ((u >> 16) & 1u);   // round-nearest-even
  return (unsigned short)(u >> 16);
}

// ---- dispatch 2: conv (232) || hist+rank+vocab-cache (6250) || prep (3) ----
__global__ __launch_bounds__(256) void conv_hist_prep_kernel(
    const float* __restrict__ Wfc, const float* __restrict__ W1,
    const float* __restrict__ W2, unsigned short* __restrict__ Wt,
    unsigned short* __restrict__ W1t, unsigned short* __restrict__ W2t,
    const int* __restrict__ src, const int* __restrict__ dst,
    const int* __restrict__ h0, int* __restrict__ cnt,
    unsigned short* __restrict__ rank16,
    unsigned short* __restrict__ vsrc16, unsigned short* __restrict__ vdst16,
    const float* __restrict__ al, const float* __restrict__ ar,
    float* __restrict__ wl, float* __restrict__ wr)
{
  if (blockIdx.x < CONV_BLOCKS) {
    int i = blockIdx.x * 256 + threadIdx.x;
    if (i < HDIM * FDIM) {
      int c = i / HDIM, k = i % HDIM;
      Wt[i] = f2bf(Wfc[(size_t)k * FDIM + c]);
    } else if (i < HDIM * FDIM + 128 * 64) {
      int j = i - HDIM * FDIM;
      int c = j / 64, k = j % 64;
      W1t[j] = f2bf(W1[(size_t)k * 128 + c]);
    } else if (i < CONV_ELEMS) {
      int j = i - HDIM * FDIM - 128 * 64;
      int c = j / 128, k = j % 128;
      W2t[j] = f2bf(W2[(size_t)k * 16 + c]);
    }
    return;
  }
  if (blockIdx.x < CONV_BLOCKS + HIST_BLOCKS) {
    int e = (blockIdx.x - CONV_BLOCKS) * 256 + threadIdx.x;
    if (e < NEDGES) {
      int s = src[e], d = dst[e];
      rank16[e]  = (unsigned short)atomicAdd(&cnt[d], 1);
      vsrc16[e]  = (unsigned short)h0[s];     // vocab < 65536
      vdst16[e]  = (unsigned short)h0[d];
    }
    return;
  }
  // prep: wl[h][k] = sum_c Wfc[k][h*64+c] * al[h*64+c]
  int t = (blockIdx.x - CONV_BLOCKS - HIST_BLOCKS) * 256 + threadIdx.x;  // 0..767
  if (t >= 3 * 256) return;
  int h = t >> 8, k = t & 255;
  const float* a_l = &al[h * 64];
  const float* a_r = &ar[h * 64];
  const float* row = &Wfc[(size_t)k * FDIM + h * 64];
  float sl = 0.f, sr = 0.f;
#pragma unroll 16
  for (int c = 0; c < 64; ++c) {
    float w = row[c];
    sl += w * a_l[c];
    sr += w * a_r[c];
  }
  wl[h * 256 + k] = sl;
  wr[h * 256 + k] = sr;
}

// ---- dispatch 3: single-pass scan (98, redundant prefix) || elvr (12500) ---
__global__ __launch_bounds__(256) void scan_elvr_kernel(
    const int* __restrict__ cnt, int* __restrict__ offs,
    const float* __restrict__ emb, const float* __restrict__ wl,
    const float* __restrict__ wr, float4* __restrict__ elv4,
    float4* __restrict__ erv4)
{
  if (blockIdx.x < NB) {
    __shared__ int sd[256];
    __shared__ int base_sh;
    const int i = blockIdx.x, t = threadIdx.x;
    const int pre = i * 1024;                 // multiple of 1024
    int s = 0;
    for (int j = t * 4; j < pre; j += 1024) {
      int4 v = *reinterpret_cast<const int4*>(&cnt[j]);
      s += v.x + v.y + v.z + v.w;
    }
    sd[t] = s;
    __syncthreads();
    for (int o = 128; o > 0; o >>= 1) {
      if (t < o) sd[t] += sd[t + o];
      __syncthreads();
    }
    if (t == 0) base_sh = sd[0];
    __syncthreads();
    const int base = base_sh;
    __syncthreads();                          // done with sd's old contents
    int bstart = pre + t * 4;
    int c[4];
    int ts = 0;
#pragma unroll
    for (int j = 0; j < 4; ++j) {
      c[j] = (bstart + j < NNODES) ? cnt[bstart + j] : 0;
      ts += c[j];
    }
    sd[t] = ts;
    __syncthreads();
    for (int o = 1; o < 256; o <<= 1) {
      int v = (t >= o) ? sd[t - o] : 0;
      __syncthreads();
      sd[t] += v;
      __syncthreads();
    }
    int run = sd[t] - ts + base;
#pragma unroll
    for (int j = 0; j < 4; ++j) {
      if (bstart + j < NNODES) offs[bstart + j] = run;
      run += c[j];
    }
    if (i == NB - 1 && t == 255) offs[NNODES] = base + sd[255];
    return;
  }
  // elvr role: elv[v] = emb[v]·wl (per head), erv likewise — pure fp32 GEMV
  int v = (blockIdx.x - NB) * 4 + (threadIdx.x >> 6);
  int lane = threadIdx.x & 63;
  if (v >= VOCAB) return;
  const float* er_ = &emb[(size_t)v * HDIM];
  float e0 = er_[lane], e1 = er_[64 + lane], e2 = er_[128 + lane], e3 = er_[192 + lane];
  float sl[3], sr[3];
#pragma unroll
  for (int h = 0; h < 3; ++h) {
    const float* wlh = &wl[h * 256];
    const float* wrh = &wr[h * 256];
    sl[h] = e0 * wlh[lane] + e1 * wlh[64 + lane] + e2 * wlh[128 + lane] + e3 * wlh[192 + lane];
    sr[h] = e0 * wrh[lane] + e1 * wrh[64 + lane] + e2 * wrh[128 + lane] + e3 * wrh[192 + lane];
  }
#pragma unroll
  for (int s = 32; s > 0; s >>= 1) {
#pragma unroll
    for (int h = 0; h < 3; ++h) {
      sl[h] += __shfl_xor(sl[h], s, 64);
      sr[h] += __shfl_xor(sr[h], s, 64);
    }
  }
  if (lane == 0) {
    elv4[v] = make_float4(sl[0], sl[1], sl[2], 0.f);
    erv4[v] = make_float4(sr[0], sr[1], sr[2], 0.f);
  }
}

// ---- dispatch 4: proj GEMM (782) || scatter+weights 8-wide (782) -----------
__global__ __launch_bounds__(256) void proj_scatter_kernel(
    const float* __restrict__ emb,              // [V][256] f32
    const unsigned short* __restrict__ Wt,      // [192][256] bf16
    unsigned short* __restrict__ proj_bf,       // [V][192]
    const int* __restrict__ dst,
    const unsigned short* __restrict__ rank16,
    const unsigned short* __restrict__ vsrc16,
    const unsigned short* __restrict__ vdst16,
    const int* __restrict__ offs,
    const float4* __restrict__ elv4, const float4* __restrict__ erv4,
    uint2* __restrict__ wrec)
{
  if (blockIdx.x >= PROJ_BLOCKS) {
    int t = (blockIdx.x - PROJ_BLOCKS) * 256 + threadIdx.x;
    int e0 = t * 8;
    if (e0 >= NEDGES) return;                 // NEDGES % 8 == 0
    // level 0: coalesced vector loads (all independent)
    int4    dA = *reinterpret_cast<const int4*>(&dst[e0]);
    int4    dB = *reinterpret_cast<const int4*>(&dst[e0 + 4]);
    ushort4 rA = *reinterpret_cast<const ushort4*>(&rank16[e0]);
    ushort4 rB = *reinterpret_cast<const ushort4*>(&rank16[e0 + 4]);
    ushort4 sA = *reinterpret_cast<const ushort4*>(&vsrc16[e0]);
    ushort4 sB = *reinterpret_cast<const ushort4*>(&vsrc16[e0 + 4]);
    ushort4 vA = *reinterpret_cast<const ushort4*>(&vdst16[e0]);
    ushort4 vB = *reinterpret_cast<const ushort4*>(&vdst16[e0 + 4]);
    int dd[8] = {dA.x, dA.y, dA.z, dA.w, dB.x, dB.y, dB.z, dB.w};
    int rr[8] = {rA.x, rA.y, rA.z, rA.w, rB.x, rB.y, rB.z, rB.w};
    int vs[8] = {sA.x, sA.y, sA.z, sA.w, sB.x, sB.y, sB.z, sB.w};
    int vd[8] = {vA.x, vA.y, vA.z, vA.w, vB.x, vB.y, vB.z, vB.w};
    // level 1: 24 independent random loads in flight
    float4 el[8], er[8];
    int of[8];
#pragma unroll
    for (int j = 0; j < 8; ++j) {
      el[j] = elv4[vs[j]];
      er[j] = erv4[vd[j]];
      of[j] = offs[dd[j]];
    }
    // compute + scattered writes
#pragma unroll
    for (int j = 0; j < 8; ++j) {
      float e0f = el[j].x + er[j].x, e1f = el[j].y + er[j].y, e2f = el[j].z + er[j].z;
      e0f = e0f > 0.f ? e0f : 0.2f * e0f;   // leaky_relu 0.2
      e1f = e1f > 0.f ? e1f : 0.2f * e1f;
      e2f = e2f > 0.f ? e2f : 0.2f * e2f;
      unsigned short u0 = f2bf(__expf(e0f));
      unsigned short u1 = f2bf(__expf(e1f));
      unsigned short u2 = f2bf(__expf(e2f));
      wrec[of[j] + rr[j]] = make_uint2((unsigned)vs[j] | ((unsigned)u0 << 16),
                                       (unsigned)u1 | ((unsigned)u2 << 16));
    }
    return;
  }
  const int wave = threadIdx.x >> 6;
  const int lane = threadIdx.x & 63;
  const int row0 = blockIdx.x * 64 + wave * 16;
  const int cb = lane & 15;
  const int q  = lane >> 4;
  int arow = row0 + cb;
  if (arow >= VOCAB) arow = VOCAB - 1;          // clamp loads; stores guarded
  const int kgrp = q * 8;

  f32x4 acc[12];
#pragma unroll
  for (int c = 0; c < 12; ++c) acc[c] = (f32x4){0.f, 0.f, 0.f, 0.f};

  const float* arow_p = &emb[(size_t)arow * HDIM + kgrp];
  const unsigned short* bcol_p = &Wt[(size_t)cb * HDIM + kgrp];

#pragma unroll
  for (int ks = 0; ks < 8; ++ks) {
    float4 f0 = *reinterpret_cast<const float4*>(arow_p + ks * 32);
    float4 f1 = *reinterpret_cast<const float4*>(arow_p + ks * 32 + 4);
    bf16x8 a;
    a[0] = (short)f2bf(f0.x); a[1] = (short)f2bf(f0.y);
    a[2] = (short)f2bf(f0.z); a[3] = (short)f2bf(f0.w);
    a[4] = (short)f2bf(f1.x); a[5] = (short)f2bf(f1.y);
    a[6] = (short)f2bf(f1.z); a[7] = (short)f2bf(f1.w);
#pragma unroll
    for (int c = 0; c < 12; ++c) {
      bf16x8 b = *reinterpret_cast<const bf16x8*>(bcol_p + (size_t)c * 16 * HDIM + ks * 32);
      acc[c] = __builtin_amdgcn_mfma_f32_16x16x32_bf16(a, b, acc[c], 0, 0, 0);
    }
  }

  const int rb = row0 + 4 * q;
#pragma unroll
  for (int i = 0; i < 4; ++i) {
    int r = rb + i;
    if (r < VOCAB) {
#pragma unroll
      for (int c = 0; c < 12; ++c)
        proj_bf[(size_t)r * FDIM + c * 16 + cb] = f2bf(acc[c][i]);
    }
  }
}

// ---- per-node aggregation: head-major lanes, 8B gathers, bit-trick bf16 ----
// lane = (head, 4-feature group): lane<48 active (48..63 mirror head 2).
// One uint2 (4 bf16) gather per lane per edge; w selected per head.
__global__ __launch_bounds__(256) void aggregate_kernel(
    const uint2* __restrict__ wrec, const int* __restrict__ offs,
    const unsigned short* __restrict__ proj_bf, const float* __restrict__ bias_gat,
    unsigned short* __restrict__ h2bf, int N)
{
  const int lane = threadIdx.x & 63;
  const int n = blockIdx.x * 4 + (threadIdx.x >> 6);
  if (n >= N) return;
  int head = lane >> 4; if (head > 2) head = 2;   // lanes 48-63 mirror head 2
  const int sub = lane & 15;
  const char* pbase = (const char*)proj_bf;
  const unsigned lane_off = (unsigned)(head * 128 + sub * 8);   // bytes in row

  int lo = offs[n], hi = offs[n + 1];
  float a0 = 0.f, a1 = 0.f, a2 = 0.f, a3 = 0.f, d = 0.f;

  int i = lo;
  for (; i + 8 <= hi; i += 8) {
    uint2 r[8];
#pragma unroll
    for (int j = 0; j < 8; ++j) r[j] = wrec[i + j];   // uniform addr -> broadcast
    const char* pa[8];
    float w[8];
#pragma unroll
    for (int j = 0; j < 8; ++j) {
      unsigned v = r[j].x & 0xFFFFu;
      pa[j] = pbase + (size_t)(v * 384u + lane_off);
      unsigned wb = (head == 0) ? (r[j].x & 0xFFFF0000u)
                  : (head == 1) ? (r[j].y << 16)
                                : (r[j].y & 0xFFFF0000u);
      w[j] = __uint_as_float(wb);
    }
    uint2 g[8];
#pragma unroll
    for (int j = 0; j < 8; ++j)                        // 8 gathers in flight
      g[j] = *reinterpret_cast<const uint2*>(pa[j]);
#pragma unroll
    for (int j = 0; j < 8; ++j) {
      a0 += w[j] * __uint_as_float(g[j].x << 16);
      a1 += w[j] * __uint_as_float(g[j].x & 0xFFFF0000u);
      a2 += w[j] * __uint_as_float(g[j].y << 16);
      a3 += w[j] * __uint_as_float(g[j].y & 0xFFFF0000u);
      d  += w[j];
    }
  }
  for (; i < hi; ++i) {
    uint2 r = wrec[i];
    unsigned v = r.x & 0xFFFFu;
    unsigned wb = (head == 0) ? (r.x & 0xFFFF0000u)
                : (head == 1) ? (r.y << 16)
                              : (r.y & 0xFFFF0000u);
    float w = __uint_as_float(wb);
    uint2 g = *reinterpret_cast<const uint2*>(pbase + (size_t)(v * 384u + lane_off));
    a0 += w * __uint_as_float(g.x << 16);
    a1 += w * __uint_as_float(g.x & 0xFFFF0000u);
    a2 += w * __uint_as_float(g.y << 16);
    a3 += w * __uint_as_float(g.y & 0xFFFF0000u);
    d  += w;
  }

  float inv = d > 0.f ? 1.f / d : 0.f;       // guard 0-in-degree
  float4 bb = *reinterpret_cast<const float4*>(&bias_gat[head * 64 + sub * 4]);
  float r0 = fmaxf(a0 * inv + bb.x, 0.f);
  float r1 = fmaxf(a1 * inv + bb.y, 0.f);
  float r2 = fmaxf(a2 * inv + bb.z, 0.f);
  float r3 = fmaxf(a3 * inv + bb.w, 0.f);
  // mean over heads: lanes 0-15 pull head1 (lane+16) and head2 (lane+32)
  float s0 = r0 + __shfl(r0, lane + 16, 64) + __shfl(r0, lane + 32, 64);
  float s1 = r1 + __shfl(r1, lane + 16, 64) + __shfl(r1, lane + 32, 64);
  float s2 = r2 + __shfl(r2, lane + 16, 64) + __shfl(r2, lane + 32, 64);
  float s3 = r3 + __shfl(r3, lane + 16, 64) + __shfl(r3, lane + 32, 64);
  if (lane < 16) {
    ushort4 o;
    o.x = f2bf(s0 * (1.f / 3.f));
    o.y = f2bf(s1 * (1.f / 3.f));
    o.z = f2bf(s2 * (1.f / 3.f));
    o.w = f2bf(s3 * (1.f / 3.f));
    *reinterpret_cast<ushort4*>(&h2bf[(size_t)n * 64 + sub * 4]) = o;
  }
}

// ---- MLP via MFMA: relu(h2@W1+b1)@W2+b2 + graph atomics --------------------
__global__ __launch_bounds__(256) void post_mfma_kernel(
    const unsigned short* __restrict__ h2bf,   // [N][64]
    const unsigned short* __restrict__ W1t,    // [128][64]
    const float* __restrict__ b1,
    const unsigned short* __restrict__ W2t,    // [16][128]
    const float* __restrict__ b2, const int* __restrict__ gid,
    float* __restrict__ sums_priv, float* __restrict__ counts_priv, int N)
{
  __shared__ unsigned short z_lds[64 * 128];
  const int wave = threadIdx.x >> 6;
  const int lane = threadIdx.x & 63;
  const int r = lane & 15;
  const int q = lane >> 4;
  const int kg = q * 8;
  const int rw0 = blockIdx.x * 64 + wave * 16;

  int arow = rw0 + r;
  if (arow >= N) arow = N - 1;       // clamp loads; stores guarded

  f32x4 acc1[8];
#pragma unroll
  for (int c = 0; c < 8; ++c) acc1[c] = (f32x4){0.f, 0.f, 0.f, 0.f};

#pragma unroll
  for (int ks = 0; ks < 2; ++ks) {
    bf16x8 a = *reinterpret_cast<const bf16x8*>(&h2bf[(size_t)arow * 64 + kg + ks * 32]);
#pragma unroll
    for (int c = 0; c < 8; ++c) {
      bf16x8 b = *reinterpret_cast<const bf16x8*>(&W1t[(size_t)(c * 16 + r) * 64 + kg + ks * 32]);
      acc1[c] = __builtin_amdgcn_mfma_f32_16x16x32_bf16(a, b, acc1[c], 0, 0, 0);
    }
  }
#pragma unroll
  for (int c = 0; c < 8; ++c) {
    float bb = b1[c * 16 + r];
#pragma unroll
    for (int i = 0; i < 4; ++i) {
      float z = acc1[c][i] + bb;
      z = z > 0.f ? z : 0.f;
      z_lds[(wave * 16 + 4 * q + i) * 128 + c * 16 + r] = f2bf(z);
    }
  }
  __syncthreads();

  f32x4 acc2 = (f32x4){0.f, 0.f, 0.f, 0.f};
#pragma unroll
  for (int ks = 0; ks < 4; ++ks) {
    bf16x8 a = *reinterpret_cast<const bf16x8*>(&z_lds[(wave * 16 + r) * 128 + kg + ks * 32]);
    bf16x8 b = *reinterpret_cast<const bf16x8*>(&W2t[(size_t)r * 128 + kg + ks * 32]);
    acc2 = __builtin_amdgcn_mfma_f32_16x16x32_bf16(a, b, acc2, 0, 0, 0);
  }
  const int part = blockIdx.x & (NPART - 1);
  float bb2 = b2[r];
#pragma unroll
  for (int i = 0; i < 4; ++i) {
    int row = rw0 + 4 * q + i;
    if (row < N) {
      int g = gid[row];
      atomicAdd(&sums_priv[(part * NGRAPH + g) * 16 + r], acc2[i] + bb2);
      if (r == 0) atomicAdd(&counts_priv[part * NGRAPH + g], 1.f);
    }
  }
}

// ---------------- reduce privatized graph sums -> output --------------------
__global__ void finalize_kernel(const float* __restrict__ sums_priv,
                                const float* __restrict__ counts_priv,
                                float* __restrict__ out)
{
  int j = threadIdx.x;            // 0..1023  (g*16 + col)
  int g = j >> 4;
  float s = 0.f, c = 0.f;
  for (int p = 0; p < NPART; ++p) {
    s += sums_priv[p * NGRAPH * 16 + j];
    c += counts_priv[p * NGRAPH + g];
  }
  out[j] = s / fmaxf(c, 1.f);
}

extern "C" void kernel_launch(void* const* d_in, const int* in_sizes, int n_in,
                              void* d_out, int out_size, void* d_ws, size_t ws_size,
                              hipStream_t stream)
{
  const int*   h0  = (const int*)  d_in[0];
  const int*   src = (const int*)  d_in[1];
  const int*   dst = (const int*)  d_in[2];
  const int*   gid = (const int*)  d_in[3];
  const float* emb = (const float*)d_in[4];
  const float* Wfc = (const float*)d_in[5];
  const float* al  = (const float*)d_in[6];
  const float* ar  = (const float*)d_in[7];
  const float* bg  = (const float*)d_in[8];
  const float* W1  = (const float*)d_in[9];
  const float* b1  = (const float*)d_in[10];
  const float* W2  = (const float*)d_in[11];
  const float* b2  = (const float*)d_in[12];
  float* out = (float*)d_out;

  char* ws = (char*)d_ws;
  size_t off = 0;
  auto alloc = [&](size_t bytes) -> void* {
    off = (off + 255) & ~(size_t)255;
    void* p = ws + off;
    off += bytes;
    return p;
  };
  // contiguous zero region: cnt | sums | cnts  (one memset)
  const size_t CNT_B  = (size_t)NNODES * 4;                 // 400000
  const size_t CNT_BP = (CNT_B + 255) & ~(size_t)255;       // 400128
  const size_t SUMS_B = (size_t)NPART * NGRAPH * 16 * 4;    // 262144
  const size_t ZB     = CNT_BP + SUMS_B + (size_t)NPART * NGRAPH * 4;
  char*  zero_base = (char*)alloc(ZB);
  int*   cnt  = (int*)zero_base;
  float* sums = (float*)(zero_base + CNT_BP);
  float* cnts = (float*)(zero_base + CNT_BP + SUMS_B);

  unsigned short* Wt      = (unsigned short*)alloc((size_t)FDIM * HDIM * 2);
  unsigned short* W1t     = (unsigned short*)alloc((size_t)128 * 64 * 2);
  unsigned short* W2t     = (unsigned short*)alloc((size_t)16 * 128 * 2);
  unsigned short* proj_bf = (unsigned short*)alloc((size_t)VOCAB * FDIM * 2);
  unsigned short* h2bf    = (unsigned short*)alloc((size_t)NNODES * 64 * 2);
  unsigned short* rank16  = (unsigned short*)alloc((size_t)NEDGES * 2);
  unsigned short* vsrc16  = (unsigned short*)alloc((size_t)NEDGES * 2);
  unsigned short* vdst16  = (unsigned short*)alloc((size_t)NEDGES * 2);
  uint2*  wrec   = (uint2*) alloc((size_t)NEDGES * 8);
  float4* elv4   = (float4*)alloc((size_t)VOCAB * 16);
  float4* erv4   = (float4*)alloc((size_t)VOCAB * 16);
  float*  wl     = (float*) alloc((size_t)3 * 256 * 4);
  float*  wr     = (float*) alloc((size_t)3 * 256 * 4);
  int*    offs   = (int*)   alloc((size_t)(NNODES + 1) * 4);

  hipMemsetAsync(zero_base, 0, ZB, stream);

  conv_hist_prep_kernel<<<CONV_BLOCKS + HIST_BLOCKS + PREP_BLOCKS, 256, 0, stream>>>(
      Wfc, W1, W2, Wt, W1t, W2t, src, dst, h0, cnt, rank16, vsrc16, vdst16,
      al, ar, wl, wr);
  scan_elvr_kernel<<<NB + ELVR_BLOCKS, 256, 0, stream>>>(
      cnt, offs, emb, wl, wr, elv4, erv4);
  proj_scatter_kernel<<<PROJ_BLOCKS + SCAT_BLOCKS, 256, 0, stream>>>(
      emb, Wt, proj_bf, dst, rank16, vsrc16, vdst16, offs, elv4, erv4, wrec);
  aggregate_kernel<<<(NNODES + 3) / 4, 256, 0, stream>>>(wrec, offs, proj_bf,
                                                         bg, h2bf, NNODES);
  post_mfma_kernel<<<(NNODES + 63) / 64, 256, 0, stream>>>(h2bf, W1t, b1, W2t, b2, gid,
                                                           sums, cnts, NNODES);
  finalize_kernel<<<1, 1024, 0, stream>>>(sums, cnts, out);
}

// Round 17
// 322.010 us; speedup vs baseline: 1.0506x; 1.0506x over previous
//
#include <hip/hip_runtime.h>
#include <hip/hip_bf16.h>

#define NNODES 100000
#define NEDGES 1600000
#define VOCAB 50000
#define HDIM 256
#define ADIM 64
#define NHEADS 3
#define FDIM 192   // NHEADS*ADIM
#define NGRAPH 64
#define NPART 64

#define CONV_ELEMS (HDIM * FDIM + 128 * 64 + 16 * 128)   // 59392
#define CONV_BLOCKS ((CONV_ELEMS + 255) / 256)            // 232
#define HIST_BLOCKS ((NEDGES + 255) / 256)                // 6250
#define PREP_BLOCKS 3
#define ELVR_BLOCKS ((VOCAB + 3) / 4)                     // 12500
#define PROJ_BLOCKS ((VOCAB + 63) / 64)                   // 782
#define SCAT_BLOCKS ((NEDGES / 8 + 255) / 256)            // 782 (8 edges/thread)
#define NB ((NNODES + 1023) / 1024)                       // 98 scan blocks

typedef __attribute__((ext_vector_type(8))) short bf16x8;  // 8 bf16 = 4 VGPRs
typedef __attribute__((ext_vector_type(4))) float f32x4;

__device__ __forceinline__ float bf2f(unsigned short u) {
  return __uint_as_float((unsigned int)u << 16);
}
__device__ __forceinline__ unsigned short f2bf(float f) {
  unsigned int u = __float_as_uint(f);
  u += 0x7FFFu + ((u >> 16) & 1u);   // round-nearest-even
  return (unsigned short)(u >> 16);
}

// ---- dispatch 2: conv (232) || hist+rank+vocab-cache (6250) || prep (3) ----
__global__ __launch_bounds__(256) void conv_hist_prep_kernel(
    const float* __restrict__ Wfc, const float* __restrict__ W1,
    const float* __restrict__ W2, unsigned short* __restrict__ Wt,
    unsigned short* __restrict__ W1t, unsigned short* __restrict__ W2t,
    const int* __restrict__ src, const int* __restrict__ dst,
    const int* __restrict__ h0, int* __restrict__ cnt,
    unsigned short* __restrict__ rank16,
    unsigned short* __restrict__ vsrc16, unsigned short* __restrict__ vdst16,
    const float* __restrict__ al, const float* __restrict__ ar,
    float* __restrict__ wl, float* __restrict__ wr)
{
  if (blockIdx.x < CONV_BLOCKS) {
    int i = blockIdx.x * 256 + threadIdx.x;
    if (i < HDIM * FDIM) {
      int c = i / HDIM, k = i % HDIM;
      Wt[i] = f2bf(Wfc[(size_t)k * FDIM + c]);
    } else if (i < HDIM * FDIM + 128 * 64) {
      int j = i - HDIM * FDIM;
      int c = j / 64, k = j % 64;
      W1t[j] = f2bf(W1[(size_t)k * 128 + c]);
    } else if (i < CONV_ELEMS) {
      int j = i - HDIM * FDIM - 128 * 64;
      int c = j / 128, k = j % 128;
      W2t[j] = f2bf(W2[(size_t)k * 16 + c]);
    }
    return;
  }
  if (blockIdx.x < CONV_BLOCKS + HIST_BLOCKS) {
    int e = (blockIdx.x - CONV_BLOCKS) * 256 + threadIdx.x;
    if (e < NEDGES) {
      int s = src[e], d = dst[e];
      rank16[e]  = (unsigned short)atomicAdd(&cnt[d], 1);
      vsrc16[e]  = (unsigned short)h0[s];     // vocab < 65536
      vdst16[e]  = (unsigned short)h0[d];
    }
    return;
  }
  // prep: wl[h][k] = sum_c Wfc[k][h*64+c] * al[h*64+c]
  int t = (blockIdx.x - CONV_BLOCKS - HIST_BLOCKS) * 256 + threadIdx.x;  // 0..767
  if (t >= 3 * 256) return;
  int h = t >> 8, k = t & 255;
  const float* a_l = &al[h * 64];
  const float* a_r = &ar[h * 64];
  const float* row = &Wfc[(size_t)k * FDIM + h * 64];
  float sl = 0.f, sr = 0.f;
#pragma unroll 16
  for (int c = 0; c < 64; ++c) {
    float w = row[c];
    sl += w * a_l[c];
    sr += w * a_r[c];
  }
  wl[h * 256 + k] = sl;
  wr[h * 256 + k] = sr;
}

// ---- dispatch 3: single-pass scan (98, redundant prefix) || elvr (12500) ---
__global__ __launch_bounds__(256) void scan_elvr_kernel(
    const int* __restrict__ cnt, int* __restrict__ offs,
    const float* __restrict__ emb, const float* __restrict__ wl,
    const float* __restrict__ wr, float4* __restrict__ elv4,
    float4* __restrict__ erv4)
{
  if (blockIdx.x < NB) {
    __shared__ int sd[256];
    __shared__ int base_sh;
    const int i = blockIdx.x, t = threadIdx.x;
    const int pre = i * 1024;                 // multiple of 1024
    int s = 0;
    for (int j = t * 4; j < pre; j += 1024) {
      int4 v = *reinterpret_cast<const int4*>(&cnt[j]);
      s += v.x + v.y + v.z + v.w;
    }
    sd[t] = s;
    __syncthreads();
    for (int o = 128; o > 0; o >>= 1) {
      if (t < o) sd[t] += sd[t + o];
      __syncthreads();
    }
    if (t == 0) base_sh = sd[0];
    __syncthreads();
    const int base = base_sh;
    __syncthreads();                          // done with sd's old contents
    int bstart = pre + t * 4;
    int c[4];
    int ts = 0;
#pragma unroll
    for (int j = 0; j < 4; ++j) {
      c[j] = (bstart + j < NNODES) ? cnt[bstart + j] : 0;
      ts += c[j];
    }
    sd[t] = ts;
    __syncthreads();
    for (int o = 1; o < 256; o <<= 1) {
      int v = (t >= o) ? sd[t - o] : 0;
      __syncthreads();
      sd[t] += v;
      __syncthreads();
    }
    int run = sd[t] - ts + base;
#pragma unroll
    for (int j = 0; j < 4; ++j) {
      if (bstart + j < NNODES) offs[bstart + j] = run;
      run += c[j];
    }
    if (i == NB - 1 && t == 255) offs[NNODES] = base + sd[255];
    return;
  }
  // elvr role: elv[v] = emb[v]·wl (per head), erv likewise — pure fp32 GEMV
  int v = (blockIdx.x - NB) * 4 + (threadIdx.x >> 6);
  int lane = threadIdx.x & 63;
  if (v >= VOCAB) return;
  const float* er_ = &emb[(size_t)v * HDIM];
  float e0 = er_[lane], e1 = er_[64 + lane], e2 = er_[128 + lane], e3 = er_[192 + lane];
  float sl[3], sr[3];
#pragma unroll
  for (int h = 0; h < 3; ++h) {
    const float* wlh = &wl[h * 256];
    const float* wrh = &wr[h * 256];
    sl[h] = e0 * wlh[lane] + e1 * wlh[64 + lane] + e2 * wlh[128 + lane] + e3 * wlh[192 + lane];
    sr[h] = e0 * wrh[lane] + e1 * wrh[64 + lane] + e2 * wrh[128 + lane] + e3 * wrh[192 + lane];
  }
#pragma unroll
  for (int s = 32; s > 0; s >>= 1) {
#pragma unroll
    for (int h = 0; h < 3; ++h) {
      sl[h] += __shfl_xor(sl[h], s, 64);
      sr[h] += __shfl_xor(sr[h], s, 64);
    }
  }
  if (lane == 0) {
    elv4[v] = make_float4(sl[0], sl[1], sl[2], 0.f);
    erv4[v] = make_float4(sr[0], sr[1], sr[2], 0.f);
  }
}

// ---- dispatch 4: proj GEMM (782) || scatter+weights 8-wide (782) -----------
__global__ __launch_bounds__(256) void proj_scatter_kernel(
    const float* __restrict__ emb,              // [V][256] f32
    const unsigned short* __restrict__ Wt,      // [192][256] bf16
    unsigned short* __restrict__ proj_bf,       // [V][192]
    const int* __restrict__ dst,
    const unsigned short* __restrict__ rank16,
    const unsigned short* __restrict__ vsrc16,
    const unsigned short* __restrict__ vdst16,
    const int* __restrict__ offs,
    const float4* __restrict__ elv4, const float4* __restrict__ erv4,
    uint2* __restrict__ wrec)
{
  if (blockIdx.x >= PROJ_BLOCKS) {
    int t = (blockIdx.x - PROJ_BLOCKS) * 256 + threadIdx.x;
    int e0 = t * 8;
    if (e0 >= NEDGES) return;                 // NEDGES % 8 == 0
    int4    dA = *reinterpret_cast<const int4*>(&dst[e0]);
    int4    dB = *reinterpret_cast<const int4*>(&dst[e0 + 4]);
    ushort4 rA = *reinterpret_cast<const ushort4*>(&rank16[e0]);
    ushort4 rB = *reinterpret_cast<const ushort4*>(&rank16[e0 + 4]);
    ushort4 sA = *reinterpret_cast<const ushort4*>(&vsrc16[e0]);
    ushort4 sB = *reinterpret_cast<const ushort4*>(&vsrc16[e0 + 4]);
    ushort4 vA = *reinterpret_cast<const ushort4*>(&vdst16[e0]);
    ushort4 vB = *reinterpret_cast<const ushort4*>(&vdst16[e0 + 4]);
    int dd[8] = {dA.x, dA.y, dA.z, dA.w, dB.x, dB.y, dB.z, dB.w};
    int rr[8] = {rA.x, rA.y, rA.z, rA.w, rB.x, rB.y, rB.z, rB.w};
    int vs[8] = {sA.x, sA.y, sA.z, sA.w, sB.x, sB.y, sB.z, sB.w};
    int vd[8] = {vA.x, vA.y, vA.z, vA.w, vB.x, vB.y, vB.z, vB.w};
    float4 el[8], er[8];
    int of[8];
#pragma unroll
    for (int j = 0; j < 8; ++j) {            // 24 independent random loads
      el[j] = elv4[vs[j]];
      er[j] = erv4[vd[j]];
      of[j] = offs[dd[j]];
    }
#pragma unroll
    for (int j = 0; j < 8; ++j) {
      float e0f = el[j].x + er[j].x, e1f = el[j].y + er[j].y, e2f = el[j].z + er[j].z;
      e0f = e0f > 0.f ? e0f : 0.2f * e0f;   // leaky_relu 0.2
      e1f = e1f > 0.f ? e1f : 0.2f * e1f;
      e2f = e2f > 0.f ? e2f : 0.2f * e2f;
      unsigned short u0 = f2bf(__expf(e0f));
      unsigned short u1 = f2bf(__expf(e1f));
      unsigned short u2 = f2bf(__expf(e2f));
      wrec[of[j] + rr[j]] = make_uint2((unsigned)vs[j] | ((unsigned)u0 << 16),
                                       (unsigned)u1 | ((unsigned)u2 << 16));
    }
    return;
  }
  const int wave = threadIdx.x >> 6;
  const int lane = threadIdx.x & 63;
  const int row0 = blockIdx.x * 64 + wave * 16;
  const int cb = lane & 15;
  const int q  = lane >> 4;
  int arow = row0 + cb;
  if (arow >= VOCAB) arow = VOCAB - 1;          // clamp loads; stores guarded
  const int kgrp = q * 8;

  f32x4 acc[12];
#pragma unroll
  for (int c = 0; c < 12; ++c) acc[c] = (f32x4){0.f, 0.f, 0.f, 0.f};

  const float* arow_p = &emb[(size_t)arow * HDIM + kgrp];
  const unsigned short* bcol_p = &Wt[(size_t)cb * HDIM + kgrp];

#pragma unroll
  for (int ks = 0; ks < 8; ++ks) {
    float4 f0 = *reinterpret_cast<const float4*>(arow_p + ks * 32);
    float4 f1 = *reinterpret_cast<const float4*>(arow_p + ks * 32 + 4);
    bf16x8 a;
    a[0] = (short)f2bf(f0.x); a[1] = (short)f2bf(f0.y);
    a[2] = (short)f2bf(f0.z); a[3] = (short)f2bf(f0.w);
    a[4] = (short)f2bf(f1.x); a[5] = (short)f2bf(f1.y);
    a[6] = (short)f2bf(f1.z); a[7] = (short)f2bf(f1.w);
#pragma unroll
    for (int c = 0; c < 12; ++c) {
      bf16x8 b = *reinterpret_cast<const bf16x8*>(bcol_p + (size_t)c * 16 * HDIM + ks * 32);
      acc[c] = __builtin_amdgcn_mfma_f32_16x16x32_bf16(a, b, acc[c], 0, 0, 0);
    }
  }

  const int rb = row0 + 4 * q;
#pragma unroll
  for (int i = 0; i < 4; ++i) {
    int r = rb + i;
    if (r < VOCAB) {
#pragma unroll
      for (int c = 0; c < 12; ++c)
        proj_bf[(size_t)r * FDIM + c * 16 + cb] = f2bf(acc[c][i]);
    }
  }
}

// ---- per-node aggregation: gather+FMA (r15-proven form) --------------------
__global__ __launch_bounds__(256) void aggregate_kernel(
    const uint2* __restrict__ wrec, const int* __restrict__ offs,
    const unsigned short* __restrict__ proj_bf, const float* __restrict__ bias_gat,
    unsigned short* __restrict__ h2bf, int N)
{
  int lane = threadIdx.x & 63;
  int n = blockIdx.x * 4 + (threadIdx.x >> 6);
  if (n >= N) return;
  int lo = offs[n], hi = offs[n + 1];
  float a0 = 0.f, a1 = 0.f, a2 = 0.f, d0 = 0.f, d1 = 0.f, d2 = 0.f;

  int i = lo;
  for (; i + 4 <= hi; i += 4) {
    uint2 r[4];
#pragma unroll
    for (int j = 0; j < 4; ++j) r[j] = wrec[i + j];
    const unsigned short* ps[4];
#pragma unroll
    for (int j = 0; j < 4; ++j)
      ps[j] = &proj_bf[(size_t)(r[j].x & 0xFFFFu) * FDIM];
    float g0[4], g1[4], g2[4];
#pragma unroll
    for (int j = 0; j < 4; ++j) {       // 12 independent gathers in flight
      g0[j] = bf2f(ps[j][lane]);
      g1[j] = bf2f(ps[j][64 + lane]);
      g2[j] = bf2f(ps[j][128 + lane]);
    }
#pragma unroll
    for (int j = 0; j < 4; ++j) {
      float w0 = bf2f((unsigned short)(r[j].x >> 16));
      float w1 = bf2f((unsigned short)(r[j].y & 0xFFFFu));
      float w2 = bf2f((unsigned short)(r[j].y >> 16));
      a0 += w0 * g0[j]; a1 += w1 * g1[j]; a2 += w2 * g2[j];
      d0 += w0; d1 += w1; d2 += w2;     // all lanes identical -> no reduce
    }
  }
  for (; i < hi; ++i) {
    uint2 r = wrec[i];
    const unsigned short* ps = &proj_bf[(size_t)(r.x & 0xFFFFu) * FDIM];
    float w0 = bf2f((unsigned short)(r.x >> 16));
    float w1 = bf2f((unsigned short)(r.y & 0xFFFFu));
    float w2 = bf2f((unsigned short)(r.y >> 16));
    a0 += w0 * bf2f(ps[lane]);
    a1 += w1 * bf2f(ps[64 + lane]);
    a2 += w2 * bf2f(ps[128 + lane]);
    d0 += w0; d1 += w1; d2 += w2;
  }

  float i0 = d0 > 0.f ? 1.f / d0 : 0.f;   // guard 0-in-degree
  float i1 = d1 > 0.f ? 1.f / d1 : 0.f;
  float i2 = d2 > 0.f ? 1.f / d2 : 0.f;
  float r0 = a0 * i0 + bias_gat[lane];
  float r1 = a1 * i1 + bias_gat[64 + lane];
  float r2 = a2 * i2 + bias_gat[128 + lane];
  float h2 = (fmaxf(r0, 0.f) + fmaxf(r1, 0.f) + fmaxf(r2, 0.f)) * (1.f / 3.f);
  h2bf[(size_t)n * 64 + lane] = f2bf(h2);
}

// ---- MLP via MFMA: relu(h2@W1+b1)@W2+b2 + graph atomics --------------------
__global__ __launch_bounds__(256) void post_mfma_kernel(
    const unsigned short* __restrict__ h2bf,   // [N][64]
    const unsigned short* __restrict__ W1t,    // [128][64]
    const float* __restrict__ b1,
    const unsigned short* __restrict__ W2t,    // [16][128]
    const float* __restrict__ b2, const int* __restrict__ gid,
    float* __restrict__ sums_priv, float* __restrict__ counts_priv, int N)
{
  __shared__ unsigned short z_lds[64 * 128];
  const int wave = threadIdx.x >> 6;
  const int lane = threadIdx.x & 63;
  const int r = lane & 15;
  const int q = lane >> 4;
  const int kg = q * 8;
  const int rw0 = blockIdx.x * 64 + wave * 16;

  int arow = rw0 + r;
  if (arow >= N) arow = N - 1;       // clamp loads; stores guarded

  f32x4 acc1[8];
#pragma unroll
  for (int c = 0; c < 8; ++c) acc1[c] = (f32x4){0.f, 0.f, 0.f, 0.f};

#pragma unroll
  for (int ks = 0; ks < 2; ++ks) {
    bf16x8 a = *reinterpret_cast<const bf16x8*>(&h2bf[(size_t)arow * 64 + kg + ks * 32]);
#pragma unroll
    for (int c = 0; c < 8; ++c) {
      bf16x8 b = *reinterpret_cast<const bf16x8*>(&W1t[(size_t)(c * 16 + r) * 64 + kg + ks * 32]);
      acc1[c] = __builtin_amdgcn_mfma_f32_16x16x32_bf16(a, b, acc1[c], 0, 0, 0);
    }
  }
#pragma unroll
  for (int c = 0; c < 8; ++c) {
    float bb = b1[c * 16 + r];
#pragma unroll
    for (int i = 0; i < 4; ++i) {
      float z = acc1[c][i] + bb;
      z = z > 0.f ? z : 0.f;
      z_lds[(wave * 16 + 4 * q + i) * 128 + c * 16 + r] = f2bf(z);
    }
  }
  __syncthreads();

  f32x4 acc2 = (f32x4){0.f, 0.f, 0.f, 0.f};
#pragma unroll
  for (int ks = 0; ks < 4; ++ks) {
    bf16x8 a = *reinterpret_cast<const bf16x8*>(&z_lds[(wave * 16 + r) * 128 + kg + ks * 32]);
    bf16x8 b = *reinterpret_cast<const bf16x8*>(&W2t[(size_t)r * 128 + kg + ks * 32]);
    acc2 = __builtin_amdgcn_mfma_f32_16x16x32_bf16(a, b, acc2, 0, 0, 0);
  }
  const int part = blockIdx.x & (NPART - 1);
  float bb2 = b2[r];
#pragma unroll
  for (int i = 0; i < 4; ++i) {
    int row = rw0 + 4 * q + i;
    if (row < N) {
      int g = gid[row];
      atomicAdd(&sums_priv[(part * NGRAPH + g) * 16 + r], acc2[i] + bb2);
      if (r == 0) atomicAdd(&counts_priv[part * NGRAPH + g], 1.f);
    }
  }
}

// ---------------- reduce privatized graph sums -> output --------------------
__global__ void finalize_kernel(const float* __restrict__ sums_priv,
                                const float* __restrict__ counts_priv,
                                float* __restrict__ out)
{
  int j = threadIdx.x;            // 0..1023  (g*16 + col)
  int g = j >> 4;
  float s = 0.f, c = 0.f;
  for (int p = 0; p < NPART; ++p) {
    s += sums_priv[p * NGRAPH * 16 + j];
    c += counts_priv[p * NGRAPH + g];
  }
  out[j] = s / fmaxf(c, 1.f);
}

extern "C" void kernel_launch(void* const* d_in, const int* in_sizes, int n_in,
                              void* d_out, int out_size, void* d_ws, size_t ws_size,
                              hipStream_t stream)
{
  const int*   h0  = (const int*)  d_in[0];
  const int*   src = (const int*)  d_in[1];
  const int*   dst = (const int*)  d_in[2];
  const int*   gid = (const int*)  d_in[3];
  const float* emb = (const float*)d_in[4];
  const float* Wfc = (const float*)d_in[5];
  const float* al  = (const float*)d_in[6];
  const float* ar  = (const float*)d_in[7];
  const float* bg  = (const float*)d_in[8];
  const float* W1  = (const float*)d_in[9];
  const float* b1  = (const float*)d_in[10];
  const float* W2  = (const float*)d_in[11];
  const float* b2  = (const float*)d_in[12];
  float* out = (float*)d_out;

  char* ws = (char*)d_ws;
  size_t off = 0;
  auto alloc = [&](size_t bytes) -> void* {
    off = (off + 255) & ~(size_t)255;
    void* p = ws + off;
    off += bytes;
    return p;
  };
  // contiguous zero region: cnt | sums | cnts  (one memset)
  const size_t CNT_B  = (size_t)NNODES * 4;                 // 400000
  const size_t CNT_BP = (CNT_B + 255) & ~(size_t)255;       // 400128
  const size_t SUMS_B = (size_t)NPART * NGRAPH * 16 * 4;    // 262144
  const size_t ZB     = CNT_BP + SUMS_B + (size_t)NPART * NGRAPH * 4;
  char*  zero_base = (char*)alloc(ZB);
  int*   cnt  = (int*)zero_base;
  float* sums = (float*)(zero_base + CNT_BP);
  float* cnts = (float*)(zero_base + CNT_BP + SUMS_B);

  unsigned short* Wt      = (unsigned short*)alloc((size_t)FDIM * HDIM * 2);
  unsigned short* W1t     = (unsigned short*)alloc((size_t)128 * 64 * 2);
  unsigned short* W2t     = (unsigned short*)alloc((size_t)16 * 128 * 2);
  unsigned short* proj_bf = (unsigned short*)alloc((size_t)VOCAB * FDIM * 2);
  unsigned short* h2bf    = (unsigned short*)alloc((size_t)NNODES * 64 * 2);
  unsigned short* rank16  = (unsigned short*)alloc((size_t)NEDGES * 2);
  unsigned short* vsrc16  = (unsigned short*)alloc((size_t)NEDGES * 2);
  unsigned short* vdst16  = (unsigned short*)alloc((size_t)NEDGES * 2);
  uint2*  wrec   = (uint2*) alloc((size_t)NEDGES * 8);
  float4* elv4   = (float4*)alloc((size_t)VOCAB * 16);
  float4* erv4   = (float4*)alloc((size_t)VOCAB * 16);
  float*  wl     = (float*) alloc((size_t)3 * 256 * 4);
  float*  wr     = (float*) alloc((size_t)3 * 256 * 4);
  int*    offs   = (int*)   alloc((size_t)(NNODES + 1) * 4);

  hipMemsetAsync(zero_base, 0, ZB, stream);

  conv_hist_prep_kernel<<<CONV_BLOCKS + HIST_BLOCKS + PREP_BLOCKS, 256, 0, stream>>>(
      Wfc, W1, W2, Wt, W1t, W2t, src, dst, h0, cnt, rank16, vsrc16, vdst16,
      al, ar, wl, wr);
  scan_elvr_kernel<<<NB + ELVR_BLOCKS, 256, 0, stream>>>(
      cnt, offs, emb, wl, wr, elv4, erv4);
  proj_scatter_kernel<<<PROJ_BLOCKS + SCAT_BLOCKS, 256, 0, stream>>>(
      emb, Wt, proj_bf, dst, rank16, vsrc16, vdst16, offs, elv4, erv4, wrec);
  aggregate_kernel<<<(NNODES + 3) / 4, 256, 0, stream>>>(wrec, offs, proj_bf,
                                                         bg, h2bf, NNODES);
  post_mfma_kernel<<<(NNODES + 63) / 64, 256, 0, stream>>>(h2bf, W1t, b1, W2t, b2, gid,
                                                           sums, cnts, NNODES);
  finalize_kernel<<<1, 1024, 0, stream>>>(sums, cnts, out);
}

// Round 18
// 318.437 us; speedup vs baseline: 1.0624x; 1.0112x over previous
//
#include <hip/hip_runtime.h>
#include <hip/hip_bf16.h>

#define NNODES 100000
#define NEDGES 1600000
#define VOCAB 50000
#define HDIM 256
#define ADIM 64
#define NHEADS 3
#define FDIM 192   // NHEADS*ADIM
#define NGRAPH 64
#define NPART 64

#define CONV_ELEMS (HDIM * FDIM + 128 * 64 + 16 * 128)   // 59392
#define CONV_BLOCKS ((CONV_ELEMS + 255) / 256)            // 232
#define HIST_BLOCKS ((NEDGES + 255) / 256)                // 6250
#define PREP_BLOCKS 3
#define ELVR_BLOCKS ((VOCAB + 3) / 4)                     // 12500
#define PROJ_BLOCKS ((VOCAB + 63) / 64)                   // 782
#define SCAT_BLOCKS ((NEDGES / 8 + 255) / 256)            // 782 (8 edges/thread)
#define NB ((NNODES + 1023) / 1024)                       // 98 scan blocks

typedef __attribute__((ext_vector_type(8))) short bf16x8;  // 8 bf16 = 4 VGPRs
typedef __attribute__((ext_vector_type(4))) float f32x4;

__device__ __forceinline__ float bf2f(unsigned short u) {
  return __uint_as_float((unsigned int)u << 16);
}
__device__ __forceinline__ unsigned short f2bf(float f) {
  unsigned int u = __float_as_uint(f);
  u += 0x7FFFu + ((u >> 16) & 1u);   // round-nearest-even
  return (unsigned short)(u >> 16);
}

// ---- dispatch 2: conv (232) || hist+rank+vocab-cache (6250) || prep (3) ----
__global__ __launch_bounds__(256) void conv_hist_prep_kernel(
    const float* __restrict__ Wfc, const float* __restrict__ W1,
    const float* __restrict__ W2, unsigned short* __restrict__ Wt,
    unsigned short* __restrict__ W1t, unsigned short* __restrict__ W2t,
    const int* __restrict__ src, const int* __restrict__ dst,
    const int* __restrict__ h0, int* __restrict__ cnt,
    unsigned short* __restrict__ rank16,
    unsigned short* __restrict__ vsrc16, unsigned short* __restrict__ vdst16,
    const float* __restrict__ al, const float* __restrict__ ar,
    float* __restrict__ wl, float* __restrict__ wr)
{
  if (blockIdx.x < CONV_BLOCKS) {
    int i = blockIdx.x * 256 + threadIdx.x;
    if (i < HDIM * FDIM) {
      int c = i / HDIM, k = i % HDIM;
      Wt[i] = f2bf(Wfc[(size_t)k * FDIM + c]);
    } else if (i < HDIM * FDIM + 128 * 64) {
      int j = i - HDIM * FDIM;
      int c = j / 64, k = j % 64;
      W1t[j] = f2bf(W1[(size_t)k * 128 + c]);
    } else if (i < CONV_ELEMS) {
      int j = i - HDIM * FDIM - 128 * 64;
      int c = j / 128, k = j % 128;
      W2t[j] = f2bf(W2[(size_t)k * 16 + c]);
    }
    return;
  }
  if (blockIdx.x < CONV_BLOCKS + HIST_BLOCKS) {
    int e = (blockIdx.x - CONV_BLOCKS) * 256 + threadIdx.x;
    if (e < NEDGES) {
      int s = src[e], d = dst[e];
      rank16[e]  = (unsigned short)atomicAdd(&cnt[d], 1);
      vsrc16[e]  = (unsigned short)h0[s];     // vocab < 65536
      vdst16[e]  = (unsigned short)h0[d];
    }
    return;
  }
  // prep: wl[h][k] = sum_c Wfc[k][h*64+c] * al[h*64+c]
  int t = (blockIdx.x - CONV_BLOCKS - HIST_BLOCKS) * 256 + threadIdx.x;  // 0..767
  if (t >= 3 * 256) return;
  int h = t >> 8, k = t & 255;
  const float* a_l = &al[h * 64];
  const float* a_r = &ar[h * 64];
  const float* row = &Wfc[(size_t)k * FDIM + h * 64];
  float sl = 0.f, sr = 0.f;
#pragma unroll 16
  for (int c = 0; c < 64; ++c) {
    float w = row[c];
    sl += w * a_l[c];
    sr += w * a_r[c];
  }
  wl[h * 256 + k] = sl;
  wr[h * 256 + k] = sr;
}

// ---- dispatch 3: single-pass scan (98, redundant prefix) || elvr (12500) ---
__global__ __launch_bounds__(256) void scan_elvr_kernel(
    const int* __restrict__ cnt, int* __restrict__ offs,
    const float* __restrict__ emb, const float* __restrict__ wl,
    const float* __restrict__ wr, float4* __restrict__ elv4,
    float4* __restrict__ erv4)
{
  if (blockIdx.x < NB) {
    __shared__ int sd[256];
    __shared__ int base_sh;
    const int i = blockIdx.x, t = threadIdx.x;
    const int pre = i * 1024;                 // multiple of 1024
    int s = 0;
    for (int j = t * 4; j < pre; j += 1024) {
      int4 v = *reinterpret_cast<const int4*>(&cnt[j]);
      s += v.x + v.y + v.z + v.w;
    }
    sd[t] = s;
    __syncthreads();
    for (int o = 128; o > 0; o >>= 1) {
      if (t < o) sd[t] += sd[t + o];
      __syncthreads();
    }
    if (t == 0) base_sh = sd[0];
    __syncthreads();
    const int base = base_sh;
    __syncthreads();                          // done with sd's old contents
    int bstart = pre + t * 4;
    int c[4];
    int ts = 0;
#pragma unroll
    for (int j = 0; j < 4; ++j) {
      c[j] = (bstart + j < NNODES) ? cnt[bstart + j] : 0;
      ts += c[j];
    }
    sd[t] = ts;
    __syncthreads();
    for (int o = 1; o < 256; o <<= 1) {
      int v = (t >= o) ? sd[t - o] : 0;
      __syncthreads();
      sd[t] += v;
      __syncthreads();
    }
    int run = sd[t] - ts + base;
#pragma unroll
    for (int j = 0; j < 4; ++j) {
      if (bstart + j < NNODES) offs[bstart + j] = run;
      run += c[j];
    }
    if (i == NB - 1 && t == 255) offs[NNODES] = base + sd[255];
    return;
  }
  // elvr role: elv[v] = emb[v]·wl (per head), erv likewise — pure fp32 GEMV
  int v = (blockIdx.x - NB) * 4 + (threadIdx.x >> 6);
  int lane = threadIdx.x & 63;
  if (v >= VOCAB) return;
  const float* er_ = &emb[(size_t)v * HDIM];
  float e0 = er_[lane], e1 = er_[64 + lane], e2 = er_[128 + lane], e3 = er_[192 + lane];
  float sl[3], sr[3];
#pragma unroll
  for (int h = 0; h < 3; ++h) {
    const float* wlh = &wl[h * 256];
    const float* wrh = &wr[h * 256];
    sl[h] = e0 * wlh[lane] + e1 * wlh[64 + lane] + e2 * wlh[128 + lane] + e3 * wlh[192 + lane];
    sr[h] = e0 * wrh[lane] + e1 * wrh[64 + lane] + e2 * wrh[128 + lane] + e3 * wrh[192 + lane];
  }
#pragma unroll
  for (int s = 32; s > 0; s >>= 1) {
#pragma unroll
    for (int h = 0; h < 3; ++h) {
      sl[h] += __shfl_xor(sl[h], s, 64);
      sr[h] += __shfl_xor(sr[h], s, 64);
    }
  }
  if (lane == 0) {
    elv4[v] = make_float4(sl[0], sl[1], sl[2], 0.f);
    erv4[v] = make_float4(sr[0], sr[1], sr[2], 0.f);
  }
}

// ---- dispatch 4: proj GEMM (782) || scatter+weights 8-wide (782) -----------
__global__ __launch_bounds__(256) void proj_scatter_kernel(
    const float* __restrict__ emb,              // [V][256] f32
    const unsigned short* __restrict__ Wt,      // [192][256] bf16
    unsigned short* __restrict__ proj_bf,       // [V][192]
    const int* __restrict__ dst,
    const unsigned short* __restrict__ rank16,
    const unsigned short* __restrict__ vsrc16,
    const unsigned short* __restrict__ vdst16,
    const int* __restrict__ offs,
    const float4* __restrict__ elv4, const float4* __restrict__ erv4,
    uint2* __restrict__ wrec)
{
  if (blockIdx.x >= PROJ_BLOCKS) {
    int t = (blockIdx.x - PROJ_BLOCKS) * 256 + threadIdx.x;
    int e0 = t * 8;
    if (e0 >= NEDGES) return;                 // NEDGES % 8 == 0
    int4    dA = *reinterpret_cast<const int4*>(&dst[e0]);
    int4    dB = *reinterpret_cast<const int4*>(&dst[e0 + 4]);
    ushort4 rA = *reinterpret_cast<const ushort4*>(&rank16[e0]);
    ushort4 rB = *reinterpret_cast<const ushort4*>(&rank16[e0 + 4]);
    ushort4 sA = *reinterpret_cast<const ushort4*>(&vsrc16[e0]);
    ushort4 sB = *reinterpret_cast<const ushort4*>(&vsrc16[e0 + 4]);
    ushort4 vA = *reinterpret_cast<const ushort4*>(&vdst16[e0]);
    ushort4 vB = *reinterpret_cast<const ushort4*>(&vdst16[e0 + 4]);
    int dd[8] = {dA.x, dA.y, dA.z, dA.w, dB.x, dB.y, dB.z, dB.w};
    int rr[8] = {rA.x, rA.y, rA.z, rA.w, rB.x, rB.y, rB.z, rB.w};
    int vs[8] = {sA.x, sA.y, sA.z, sA.w, sB.x, sB.y, sB.z, sB.w};
    int vd[8] = {vA.x, vA.y, vA.z, vA.w, vB.x, vB.y, vB.z, vB.w};
    float4 el[8], er[8];
    int of[8];
#pragma unroll
    for (int j = 0; j < 8; ++j) {            // 24 independent random loads
      el[j] = elv4[vs[j]];
      er[j] = erv4[vd[j]];
      of[j] = offs[dd[j]];
    }
#pragma unroll
    for (int j = 0; j < 8; ++j) {
      float e0f = el[j].x + er[j].x, e1f = el[j].y + er[j].y, e2f = el[j].z + er[j].z;
      e0f = e0f > 0.f ? e0f : 0.2f * e0f;   // leaky_relu 0.2
      e1f = e1f > 0.f ? e1f : 0.2f * e1f;
      e2f = e2f > 0.f ? e2f : 0.2f * e2f;
      unsigned short u0 = f2bf(__expf(e0f));
      unsigned short u1 = f2bf(__expf(e1f));
      unsigned short u2 = f2bf(__expf(e2f));
      wrec[of[j] + rr[j]] = make_uint2((unsigned)vs[j] | ((unsigned)u0 << 16),
                                       (unsigned)u1 | ((unsigned)u2 << 16));
    }
    return;
  }
  const int wave = threadIdx.x >> 6;
  const int lane = threadIdx.x & 63;
  const int row0 = blockIdx.x * 64 + wave * 16;
  const int cb = lane & 15;
  const int q  = lane >> 4;
  int arow = row0 + cb;
  if (arow >= VOCAB) arow = VOCAB - 1;          // clamp loads; stores guarded
  const int kgrp = q * 8;

  f32x4 acc[12];
#pragma unroll
  for (int c = 0; c < 12; ++c) acc[c] = (f32x4){0.f, 0.f, 0.f, 0.f};

  const float* arow_p = &emb[(size_t)arow * HDIM + kgrp];
  const unsigned short* bcol_p = &Wt[(size_t)cb * HDIM + kgrp];

#pragma unroll
  for (int ks = 0; ks < 8; ++ks) {
    float4 f0 = *reinterpret_cast<const float4*>(arow_p + ks * 32);
    float4 f1 = *reinterpret_cast<const float4*>(arow_p + ks * 32 + 4);
    bf16x8 a;
    a[0] = (short)f2bf(f0.x); a[1] = (short)f2bf(f0.y);
    a[2] = (short)f2bf(f0.z); a[3] = (short)f2bf(f0.w);
    a[4] = (short)f2bf(f1.x); a[5] = (short)f2bf(f1.y);
    a[6] = (short)f2bf(f1.z); a[7] = (short)f2bf(f1.w);
#pragma unroll
    for (int c = 0; c < 12; ++c) {
      bf16x8 b = *reinterpret_cast<const bf16x8*>(bcol_p + (size_t)c * 16 * HDIM + ks * 32);
      acc[c] = __builtin_amdgcn_mfma_f32_16x16x32_bf16(a, b, acc[c], 0, 0, 0);
    }
  }

  const int rb = row0 + 4 * q;
#pragma unroll
  for (int i = 0; i < 4; ++i) {
    int r = rb + i;
    if (r < VOCAB) {
#pragma unroll
      for (int c = 0; c < 12; ++c)
        proj_bf[(size_t)r * FDIM + c * 16 + cb] = f2bf(acc[c][i]);
    }
  }
}

// ---- per-node aggregation: gather+FMA (r15 form, widened to 8-wide) --------
__global__ __launch_bounds__(256) void aggregate_kernel(
    const uint2* __restrict__ wrec, const int* __restrict__ offs,
    const unsigned short* __restrict__ proj_bf, const float* __restrict__ bias_gat,
    unsigned short* __restrict__ h2bf, int N)
{
  int lane = threadIdx.x & 63;
  int n = blockIdx.x * 4 + (threadIdx.x >> 6);
  if (n >= N) return;
  int lo = offs[n], hi = offs[n + 1];
  float a0 = 0.f, a1 = 0.f, a2 = 0.f, d0 = 0.f, d1 = 0.f, d2 = 0.f;

  int i = lo;
  for (; i + 8 <= hi; i += 8) {
    uint2 r[8];
#pragma unroll
    for (int j = 0; j < 8; ++j) r[j] = wrec[i + j];
    const unsigned short* ps[8];
#pragma unroll
    for (int j = 0; j < 8; ++j)
      ps[j] = &proj_bf[(size_t)(r[j].x & 0xFFFFu) * FDIM];
    float g0[8], g1[8], g2[8];
#pragma unroll
    for (int j = 0; j < 8; ++j) {       // 24 independent gathers in flight
      g0[j] = bf2f(ps[j][lane]);
      g1[j] = bf2f(ps[j][64 + lane]);
      g2[j] = bf2f(ps[j][128 + lane]);
    }
#pragma unroll
    for (int j = 0; j < 8; ++j) {
      float w0 = bf2f((unsigned short)(r[j].x >> 16));
      float w1 = bf2f((unsigned short)(r[j].y & 0xFFFFu));
      float w2 = bf2f((unsigned short)(r[j].y >> 16));
      a0 += w0 * g0[j]; a1 += w1 * g1[j]; a2 += w2 * g2[j];
      d0 += w0; d1 += w1; d2 += w2;     // all lanes identical -> no reduce
    }
  }
  for (; i + 4 <= hi; i += 4) {
    uint2 r[4];
#pragma unroll
    for (int j = 0; j < 4; ++j) r[j] = wrec[i + j];
    const unsigned short* ps[4];
#pragma unroll
    for (int j = 0; j < 4; ++j)
      ps[j] = &proj_bf[(size_t)(r[j].x & 0xFFFFu) * FDIM];
    float g0[4], g1[4], g2[4];
#pragma unroll
    for (int j = 0; j < 4; ++j) {
      g0[j] = bf2f(ps[j][lane]);
      g1[j] = bf2f(ps[j][64 + lane]);
      g2[j] = bf2f(ps[j][128 + lane]);
    }
#pragma unroll
    for (int j = 0; j < 4; ++j) {
      float w0 = bf2f((unsigned short)(r[j].x >> 16));
      float w1 = bf2f((unsigned short)(r[j].y & 0xFFFFu));
      float w2 = bf2f((unsigned short)(r[j].y >> 16));
      a0 += w0 * g0[j]; a1 += w1 * g1[j]; a2 += w2 * g2[j];
      d0 += w0; d1 += w1; d2 += w2;
    }
  }
  for (; i < hi; ++i) {
    uint2 r = wrec[i];
    const unsigned short* ps = &proj_bf[(size_t)(r.x & 0xFFFFu) * FDIM];
    float w0 = bf2f((unsigned short)(r.x >> 16));
    float w1 = bf2f((unsigned short)(r.y & 0xFFFFu));
    float w2 = bf2f((unsigned short)(r.y >> 16));
    a0 += w0 * bf2f(ps[lane]);
    a1 += w1 * bf2f(ps[64 + lane]);
    a2 += w2 * bf2f(ps[128 + lane]);
    d0 += w0; d1 += w1; d2 += w2;
  }

  float i0 = d0 > 0.f ? 1.f / d0 : 0.f;   // guard 0-in-degree
  float i1 = d1 > 0.f ? 1.f / d1 : 0.f;
  float i2 = d2 > 0.f ? 1.f / d2 : 0.f;
  float r0 = a0 * i0 + bias_gat[lane];
  float r1 = a1 * i1 + bias_gat[64 + lane];
  float r2 = a2 * i2 + bias_gat[128 + lane];
  float h2 = (fmaxf(r0, 0.f) + fmaxf(r1, 0.f) + fmaxf(r2, 0.f)) * (1.f / 3.f);
  h2bf[(size_t)n * 64 + lane] = f2bf(h2);
}

// ---- MLP via MFMA: relu(h2@W1+b1)@W2+b2 + graph atomics --------------------
__global__ __launch_bounds__(256) void post_mfma_kernel(
    const unsigned short* __restrict__ h2bf,   // [N][64]
    const unsigned short* __restrict__ W1t,    // [128][64]
    const float* __restrict__ b1,
    const unsigned short* __restrict__ W2t,    // [16][128]
    const float* __restrict__ b2, const int* __restrict__ gid,
    float* __restrict__ sums_priv, float* __restrict__ counts_priv, int N)
{
  __shared__ unsigned short z_lds[64 * 128];
  const int wave = threadIdx.x >> 6;
  const int lane = threadIdx.x & 63;
  const int r = lane & 15;
  const int q = lane >> 4;
  const int kg = q * 8;
  const int rw0 = blockIdx.x * 64 + wave * 16;

  int arow = rw0 + r;
  if (arow >= N) arow = N - 1;       // clamp loads; stores guarded

  f32x4 acc1[8];
#pragma unroll
  for (int c = 0; c < 8; ++c) acc1[c] = (f32x4){0.f, 0.f, 0.f, 0.f};

#pragma unroll
  for (int ks = 0; ks < 2; ++ks) {
    bf16x8 a = *reinterpret_cast<const bf16x8*>(&h2bf[(size_t)arow * 64 + kg + ks * 32]);
#pragma unroll
    for (int c = 0; c < 8; ++c) {
      bf16x8 b = *reinterpret_cast<const bf16x8*>(&W1t[(size_t)(c * 16 + r) * 64 + kg + ks * 32]);
      acc1[c] = __builtin_amdgcn_mfma_f32_16x16x32_bf16(a, b, acc1[c], 0, 0, 0);
    }
  }
#pragma unroll
  for (int c = 0; c < 8; ++c) {
    float bb = b1[c * 16 + r];
#pragma unroll
    for (int i = 0; i < 4; ++i) {
      float z = acc1[c][i] + bb;
      z = z > 0.f ? z : 0.f;
      z_lds[(wave * 16 + 4 * q + i) * 128 + c * 16 + r] = f2bf(z);
    }
  }
  __syncthreads();

  f32x4 acc2 = (f32x4){0.f, 0.f, 0.f, 0.f};
#pragma unroll
  for (int ks = 0; ks < 4; ++ks) {
    bf16x8 a = *reinterpret_cast<const bf16x8*>(&z_lds[(wave * 16 + r) * 128 + kg + ks * 32]);
    bf16x8 b = *reinterpret_cast<const bf16x8*>(&W2t[(size_t)r * 128 + kg + ks * 32]);
    acc2 = __builtin_amdgcn_mfma_f32_16x16x32_bf16(a, b, acc2, 0, 0, 0);
  }
  const int part = blockIdx.x & (NPART - 1);
  float bb2 = b2[r];
#pragma unroll
  for (int i = 0; i < 4; ++i) {
    int row = rw0 + 4 * q + i;
    if (row < N) {
      int g = gid[row];
      atomicAdd(&sums_priv[(part * NGRAPH + g) * 16 + r], acc2[i] + bb2);
      if (r == 0) atomicAdd(&counts_priv[part * NGRAPH + g], 1.f);
    }
  }
}

// ---------------- reduce privatized graph sums -> output --------------------
__global__ void finalize_kernel(const float* __restrict__ sums_priv,
                                const float* __restrict__ counts_priv,
                                float* __restrict__ out)
{
  int j = threadIdx.x;            // 0..1023  (g*16 + col)
  int g = j >> 4;
  float s = 0.f, c = 0.f;
  for (int p = 0; p < NPART; ++p) {
    s += sums_priv[p * NGRAPH * 16 + j];
    c += counts_priv[p * NGRAPH + g];
  }
  out[j] = s / fmaxf(c, 1.f);
}

extern "C" void kernel_launch(void* const* d_in, const int* in_sizes, int n_in,
                              void* d_out, int out_size, void* d_ws, size_t ws_size,
                              hipStream_t stream)
{
  const int*   h0  = (const int*)  d_in[0];
  const int*   src = (const int*)  d_in[1];
  const int*   dst = (const int*)  d_in[2];
  const int*   gid = (const int*)  d_in[3];
  const float* emb = (const float*)d_in[4];
  const float* Wfc = (const float*)d_in[5];
  const float* al  = (const float*)d_in[6];
  const float* ar  = (const float*)d_in[7];
  const float* bg  = (const float*)d_in[8];
  const float* W1  = (const float*)d_in[9];
  const float* b1  = (const float*)d_in[10];
  const float* W2  = (const float*)d_in[11];
  const float* b2  = (const float*)d_in[12];
  float* out = (float*)d_out;

  char* ws = (char*)d_ws;
  size_t off = 0;
  auto alloc = [&](size_t bytes) -> void* {
    off = (off + 255) & ~(size_t)255;
    void* p = ws + off;
    off += bytes;
    return p;
  };
  // contiguous zero region: cnt | sums | cnts  (one memset)
  const size_t CNT_B  = (size_t)NNODES * 4;                 // 400000
  const size_t CNT_BP = (CNT_B + 255) & ~(size_t)255;       // 400128
  const size_t SUMS_B = (size_t)NPART * NGRAPH * 16 * 4;    // 262144
  const size_t ZB     = CNT_BP + SUMS_B + (size_t)NPART * NGRAPH * 4;
  char*  zero_base = (char*)alloc(ZB);
  int*   cnt  = (int*)zero_base;
  float* sums = (float*)(zero_base + CNT_BP);
  float* cnts = (float*)(zero_base + CNT_BP + SUMS_B);

  unsigned short* Wt      = (unsigned short*)alloc((size_t)FDIM * HDIM * 2);
  unsigned short* W1t     = (unsigned short*)alloc((size_t)128 * 64 * 2);
  unsigned short* W2t     = (unsigned short*)alloc((size_t)16 * 128 * 2);
  unsigned short* proj_bf = (unsigned short*)alloc((size_t)VOCAB * FDIM * 2);
  unsigned short* h2bf    = (unsigned short*)alloc((size_t)NNODES * 64 * 2);
  unsigned short* rank16  = (unsigned short*)alloc((size_t)NEDGES * 2);
  unsigned short* vsrc16  = (unsigned short*)alloc((size_t)NEDGES * 2);
  unsigned short* vdst16  = (unsigned short*)alloc((size_t)NEDGES * 2);
  uint2*  wrec   = (uint2*) alloc((size_t)NEDGES * 8);
  float4* elv4   = (float4*)alloc((size_t)VOCAB * 16);
  float4* erv4   = (float4*)alloc((size_t)VOCAB * 16);
  float*  wl     = (float*) alloc((size_t)3 * 256 * 4);
  float*  wr     = (float*) alloc((size_t)3 * 256 * 4);
  int*    offs   = (int*)   alloc((size_t)(NNODES + 1) * 4);

  hipMemsetAsync(zero_base, 0, ZB, stream);

  conv_hist_prep_kernel<<<CONV_BLOCKS + HIST_BLOCKS + PREP_BLOCKS, 256, 0, stream>>>(
      Wfc, W1, W2, Wt, W1t, W2t, src, dst, h0, cnt, rank16, vsrc16, vdst16,
      al, ar, wl, wr);
  scan_elvr_kernel<<<NB + ELVR_BLOCKS, 256, 0, stream>>>(
      cnt, offs, emb, wl, wr, elv4, erv4);
  proj_scatter_kernel<<<PROJ_BLOCKS + SCAT_BLOCKS, 256, 0, stream>>>(
      emb, Wt, proj_bf, dst, rank16, vsrc16, vdst16, offs, elv4, erv4, wrec);
  aggregate_kernel<<<(NNODES + 3) / 4, 256, 0, stream>>>(wrec, offs, proj_bf,
                                                         bg, h2bf, NNODES);
  post_mfma_kernel<<<(NNODES + 63) / 64, 256, 0, stream>>>(h2bf, W1t, b1, W2t, b2, gid,
                                                           sums, cnts, NNODES);
  finalize_kernel<<<1, 1024, 0, stream>>>(sums, cnts, out);
}